// Round 19
// baseline (145.201 us; speedup 1.0000x reference)
//
#include <hip/hip_runtime.h>
#include <hip/hip_bf16.h>

#define DEVI __device__ __forceinline__

// Problem constants (fixed by the reference)
constexpr int Bb  = 2;
constexpr int Ss  = 2048;
constexpr int Dd  = 1024;
constexpr int Hh  = 16;
constexpr int HDh = 64;
constexpr int Mr  = Bb * Ss;      // 4096 rows in all GEMMs
constexpr float kEps = 1e-5f;
// kScale * log2(e), folded into the Q projection so flash uses raw 2^x
constexpr float kQScale = 0.18033688011112043f;

typedef unsigned short u16;
typedef unsigned int   u32;
typedef u16 u16x8 __attribute__((ext_vector_type(8)));
typedef u16 u16x4 __attribute__((ext_vector_type(4)));
typedef __attribute__((ext_vector_type(8)))  short s16x8;
typedef __attribute__((ext_vector_type(16))) float f32x16;
typedef __attribute__((ext_vector_type(4)))  u32   u32x4;

DEVI float bf2f(u16 u) {
  return __builtin_bit_cast(float, ((unsigned int)u) << 16);
}
DEVI u16 f2bf(float f) {  // round-to-nearest-even, finite values only
  unsigned int x = __builtin_bit_cast(unsigned int, f);
  return (u16)((x + 0x7FFFu + ((x >> 16) & 1u)) >> 16);
}
DEVI u32 cvt_pk_bf16(float a, float b) {  // HW packed f32x2 -> bf16x2, RNE
  u32 r;
  asm("v_cvt_pk_bf16_f32 %0, %1, %2" : "=v"(r) : "v"(a), "v"(b));
  return r;
}
DEVI float vexp2(float x) {  // 2^x on the TRANS pipe, no pre-multiply
  float r;
  asm("v_exp_f32 %0, %1" : "=v"(r) : "v"(x));
  return r;
}

// global -> LDS direct copy, 16B per lane (flash only).
DEVI void gload_lds16(const void* g, void* l) {
  __builtin_amdgcn_global_load_lds(
      (const __attribute__((address_space(1))) unsigned int*)(unsigned long long)(size_t)g,
      (__attribute__((address_space(3))) unsigned int*)(unsigned int)(size_t)l,
      16, 0, 0);
}

// ===========================================================================
// FRAGMENT-MAJOR (fm) layout, bf16 matrix [R][C]: elem [r][c] lives at u16
// offset ((r>>5)*(C/16) + (c>>4))*512 + ((r&31) + 32*((c>>3)&1))*8 + (c&7).
// A wave-load of one 32x16 frag = base + lane*16B, fully coalesced (1KB).
// ===========================================================================

// ---------------------------------------------------------------------------
// pack_all_fm: ONE launch packs 3 activations (f32 [4096][1024] -> fm bf16)
// and 4 weights (f32 [k][n] -> fm bf16 B-layout). Flat grid of 4096 blocks.
// ---------------------------------------------------------------------------
__global__ __launch_bounds__(256) void pack_all_fm(
    const float* __restrict__ X0, const float* __restrict__ X1,
    const float* __restrict__ X2,
    const float* __restrict__ W0, const float* __restrict__ W1,
    const float* __restrict__ W2, const float* __restrict__ W3,
    u16* __restrict__ Y0, u16* __restrict__ Y1, u16* __restrict__ Y2,
    u16* __restrict__ WfmBase) {
  __shared__ u16 Tl[64 * 64];
  const int t   = threadIdx.x;
  const int gid = blockIdx.x;
  if (gid < 3072) {
    // -------- activation pack --------
    const int z   = gid >> 10;
    const int rem = gid & 1023;
    const int r0  = (rem >> 4) * 64, k0 = (rem & 15) * 64;
    const float* X = z == 0 ? X0 : z == 1 ? X1 : X2;
    u16*         Y = z == 0 ? Y0 : z == 1 ? Y1 : Y2;
#pragma unroll
    for (int i = 0; i < 4; ++i) {
      const int idx = t + i * 256;
      const int r = idx >> 4, c4 = (idx & 15) << 2;
      const float4 v = *(const float4*)(X + (size_t)(r0 + r) * 1024 + k0 + c4);
      u16x4 p;
      p[0] = f2bf(v.x); p[1] = f2bf(v.y); p[2] = f2bf(v.z); p[3] = f2bf(v.w);
      *(u16x4*)&Tl[r * 64 + (c4 ^ (8 * (r & 7)))] = p;
    }
    __syncthreads();
#pragma unroll
    for (int i = 0; i < 2; ++i) {
      const int slot = t + i * 256;
      const int f = slot >> 6, l = slot & 63;
      const int l31 = l & 31, g2 = l >> 5;
      const int r = (f >> 2) * 32 + l31;
      const int c = (f & 3) * 16 + g2 * 8;
      const u16x8 v = *(const u16x8*)&Tl[r * 64 + (c ^ (8 * (r & 7)))];
      const size_t t32 = (size_t)(r0 >> 5) + (f >> 2);
      const int s = (k0 >> 4) + (f & 3);
      *(u16x8*)(Y + (t32 * 64 + s) * 512 + l * 8) = v;
    }
  } else {
    // -------- weight pack --------
    const int wz  = (gid - 3072) >> 8;
    const int rem = (gid - 3072) & 255;
    const int n0  = (rem >> 4) * 64, k0 = (rem & 15) * 64;
    const float* W = wz == 0 ? W0 : wz == 1 ? W1 : wz == 2 ? W2 : W3;
    u16* out = WfmBase + (size_t)wz * 1024 * 1024;
#pragma unroll
    for (int i = 0; i < 4; ++i) {
      const int idx = t + i * 256;
      const int r = idx >> 4, c4 = (idx & 15) << 2;   // r = k-idx, c = n-idx
      const float4 v = *(const float4*)(W + (size_t)(k0 + r) * 1024 + n0 + c4);
      u16x4 p;
      p[0] = f2bf(v.x); p[1] = f2bf(v.y); p[2] = f2bf(v.z); p[3] = f2bf(v.w);
      *(u16x4*)&Tl[r * 64 + (c4 ^ (8 * (r & 7)))] = p;
    }
    __syncthreads();
#pragma unroll
    for (int i = 0; i < 2; ++i) {
      const int slot = t + i * 256;
      const int f = slot >> 6, l = slot & 63;
      const int l31 = l & 31, g2 = l >> 5;
      const int rbase = (f & 3) * 16 + g2 * 8;         // k within tile
      const int c = (f >> 2) * 32 + l31;               // n within tile
      u16x8 o;
#pragma unroll
      for (int j = 0; j < 8; ++j) {
        const int r = rbase + j;
        o[j] = Tl[r * 64 + (((c & ~3) ^ (8 * (r & 7))) | (c & 3))];
      }
      const size_t n32 = (size_t)(n0 >> 5) + (f >> 2);
      const int s = (k0 >> 4) + (f & 3);
      *(u16x8*)(out + (n32 * 64 + s) * 512 + l * 8) = o;
    }
  }
}

// ---------------------------------------------------------------------------
// Register-staged MFMA GEMM, 128x128 block, DEPTH-3 pipeline (verified
// R9-R18). Used for the QK launch only (512 blocks = 2 blocks/CU).
// z0: Q bf16 row-major (esc-scaled); z1: K written FM into Kf.
// ---------------------------------------------------------------------------
__global__ __launch_bounds__(256, 2) void gemm_qk_k(
    const u16* __restrict__ A0, const u16* __restrict__ A1,
    const u16* __restrict__ Wt0, const u16* __restrict__ Wt1,
    const float* b0, const float* b1, void* C0, void* C1,
    float e0, float e1) {
  constexpr int K = 1024, N = 1024;
  const int z = blockIdx.z;
  const u16*   A    = z ? A1 : A0;
  const u16*   Wt   = z ? Wt1 : Wt0;
  const float* bias = z ? b1 : b0;
  void*        Cv   = z ? C1 : C0;
  const float  esc  = z ? e1 : e0;

  const int t = threadIdx.x;
  const int lane = t & 63, w = t >> 6;
  const int l31 = lane & 31, g2 = lane >> 5;
  const int id  = blockIdx.y * 8 + blockIdx.x;
  const int sid = (id & 7) * 32 + (id >> 3);
  const int m0 = (sid >> 3) * 128, n0 = (sid & 7) * 128;
  const int wr = w >> 1, wc = w & 1;

  const u16* a0p = A  + ((size_t)(m0 >> 5) + 2 * wr) * 32768 + lane * 8;
  const u16* a1p = a0p + 32768;
  const u16* w0p = Wt + ((size_t)(n0 >> 5) + 2 * wc) * 32768 + lane * 8;
  const u16* w1p = w0p + 32768;

  f32x16 acc00, acc01, acc10, acc11;
#pragma unroll
  for (int r = 0; r < 16; ++r) { acc00[r] = 0.f; acc01[r] = 0.f; acc10[r] = 0.f; acc11[r] = 0.f; }

  s16x8 X[8], Y[8], Z[8];
  auto loadset = [&](s16x8* R, int k0) {
    const int o = (k0 >> 4) * 512;
    R[0] = *(const s16x8*)(a0p + o);  R[1] = *(const s16x8*)(a0p + o + 512);
    R[2] = *(const s16x8*)(a1p + o);  R[3] = *(const s16x8*)(a1p + o + 512);
    R[4] = *(const s16x8*)(w0p + o);  R[5] = *(const s16x8*)(w0p + o + 512);
    R[6] = *(const s16x8*)(w1p + o);  R[7] = *(const s16x8*)(w1p + o + 512);
  };
  auto compute = [&](const s16x8* R) {
#pragma unroll
    for (int s = 0; s < 2; ++s) {
      // C col = m (A-op = W)
      acc00 = __builtin_amdgcn_mfma_f32_32x32x16_bf16(R[4 + s], R[0 + s], acc00, 0, 0, 0);
      acc01 = __builtin_amdgcn_mfma_f32_32x32x16_bf16(R[4 + s], R[2 + s], acc01, 0, 0, 0);
      acc10 = __builtin_amdgcn_mfma_f32_32x32x16_bf16(R[6 + s], R[0 + s], acc10, 0, 0, 0);
      acc11 = __builtin_amdgcn_mfma_f32_32x32x16_bf16(R[6 + s], R[2 + s], acc11, 0, 0, 0);
    }
  };

  loadset(X, 0); loadset(Y, 32); loadset(Z, 64);
  int k = 0;
  for (int it = 0; it < 9; ++it, k += 96) {
    compute(X); loadset(X, k + 96);
    compute(Y); loadset(Y, k + 128);
    compute(Z); loadset(Z, k + 160);
  }
  compute(X); loadset(X, 960);
  compute(Y); loadset(Y, 992);
  compute(Z);
  compute(X);
  compute(Y);

  auto storeRow = [&](const f32x16& a, int i, int j) {  // row-major bf16
    const int m = m0 + (2 * wr + j) * 32 + l31;
#pragma unroll
    for (int c = 0; c < 4; ++c) {
      const int nb = n0 + (2 * wc + i) * 32 + 8 * c + 4 * g2;
      const float4 b4 = *(const float4*)&bias[nb];
      u16x4 o;
      o[0] = f2bf((a[4 * c + 0] + b4.x) * esc); o[1] = f2bf((a[4 * c + 1] + b4.y) * esc);
      o[2] = f2bf((a[4 * c + 2] + b4.z) * esc); o[3] = f2bf((a[4 * c + 3] + b4.w) * esc);
      *(u16x4*)((u16*)Cv + (size_t)m * N + nb) = o;
    }
  };
  auto storeKfm = [&](const f32x16& a, int i, int j) {  // K in FM layout
    const int mt = (m0 >> 5) + 2 * wr + j;              // m>>5
#pragma unroll
    for (int c = 0; c < 4; ++c) {
      const int nb = n0 + (2 * wc + i) * 32 + 8 * c + 4 * g2;
      const float4 b4 = *(const float4*)&bias[nb];
      u16x4 o;
      o[0] = f2bf(a[4 * c + 0] + b4.x); o[1] = f2bf(a[4 * c + 1] + b4.y);
      o[2] = f2bf(a[4 * c + 2] + b4.z); o[3] = f2bf(a[4 * c + 3] + b4.w);
      const int nq = (n0 >> 4) + (2 * wc + i) * 2 + (c >> 1);  // n>>4
      u16* dst = (u16*)Cv + ((size_t)mt * 64 + nq) * 512 +
                 (l31 + 32 * (c & 1)) * 8 + 4 * g2;
      *(u16x4*)dst = o;
    }
  };
  if (z == 1) {
    storeKfm(acc00, 0, 0); storeKfm(acc01, 0, 1); storeKfm(acc10, 1, 0); storeKfm(acc11, 1, 1);
  } else {
    storeRow(acc00, 0, 0); storeRow(acc01, 0, 1); storeRow(acc10, 1, 0); storeRow(acc11, 1, 1);
  }
}

// ---------------------------------------------------------------------------
// SPLIT-M register GEMM: 64x128 block -> 512 blocks = 2 blocks/CU (the
// 128x128 version ran 256 blocks = 1/CU, half-idle). 4 waves, each owns a
// 64x32 tile (2 m-subtiles x 1 n-subtile = wave index w): 4 MFMA + 6 fm
// loads per 32-k chunk, same verified depth-3 X/Y/Z schedule.
// MODE 0: bf16 row-major out (o-projection). MODE 1: V^T FM into Vf.
// ---------------------------------------------------------------------------
template <int MODE>
__global__ __launch_bounds__(256, 2) void gemm_half_k(
    const u16* __restrict__ A, const u16* __restrict__ Wt,
    const float* __restrict__ bias, void* Cv) {
  constexpr int K = 1024, N = 1024;
  const int t = threadIdx.x;
  const int lane = t & 63, w = t >> 6;   // w = n-subtile 0..3
  const int l31 = lane & 31, g2 = lane >> 5;
  const int id  = blockIdx.y * 8 + blockIdx.x;        // grid (8, 64)
  const int sid = (id & 7) * 64 + (id >> 3);          // XCD chunk 64
  const int m0 = (sid >> 3) * 64, n0 = (sid & 7) * 128;

  const u16* a0p = A  + ((size_t)(m0 >> 5)) * 32768 + lane * 8;
  const u16* a1p = a0p + 32768;
  const u16* w0p = Wt + ((size_t)(n0 >> 5) + w) * 32768 + lane * 8;

  f32x16 acc0, acc1;
#pragma unroll
  for (int r = 0; r < 16; ++r) { acc0[r] = 0.f; acc1[r] = 0.f; }

  s16x8 X[6], Y[6], Z[6];
  auto loadset = [&](s16x8* R, int k0) {
    const int o = (k0 >> 4) * 512;
    R[0] = *(const s16x8*)(a0p + o);  R[1] = *(const s16x8*)(a0p + o + 512);
    R[2] = *(const s16x8*)(a1p + o);  R[3] = *(const s16x8*)(a1p + o + 512);
    R[4] = *(const s16x8*)(w0p + o);  R[5] = *(const s16x8*)(w0p + o + 512);
  };
  auto compute = [&](const s16x8* R) {
#pragma unroll
    for (int s = 0; s < 2; ++s) {
      if constexpr (MODE == 1) {
        // C col = n (A-op = X)
        acc0 = __builtin_amdgcn_mfma_f32_32x32x16_bf16(R[0 + s], R[4 + s], acc0, 0, 0, 0);
        acc1 = __builtin_amdgcn_mfma_f32_32x32x16_bf16(R[2 + s], R[4 + s], acc1, 0, 0, 0);
      } else {
        // C col = m (A-op = W)
        acc0 = __builtin_amdgcn_mfma_f32_32x32x16_bf16(R[4 + s], R[0 + s], acc0, 0, 0, 0);
        acc1 = __builtin_amdgcn_mfma_f32_32x32x16_bf16(R[4 + s], R[2 + s], acc1, 0, 0, 0);
      }
    }
  };

  loadset(X, 0); loadset(Y, 32); loadset(Z, 64);
  int k = 0;
  for (int it = 0; it < 9; ++it, k += 96) {
    compute(X); loadset(X, k + 96);
    compute(Y); loadset(Y, k + 128);
    compute(Z); loadset(Z, k + 160);
  }
  compute(X); loadset(X, 960);
  compute(Y); loadset(Y, 992);
  compute(Z);
  compute(X);
  compute(Y);

  if constexpr (MODE == 1) {
    // V^T FM over per-b matrix [nn=1024][s=2048] (same math as verified
    // storeVfm with wc->w, wr->0, i = m-subtile j)
    auto storeVfm = [&](const f32x16& a, int j) {
      const int nn = n0 + w * 32 + l31;
      const float bn = bias[nn];
      const int nnT = (n0 >> 5) + w;
      const int sb  = ((m0 & 2047) + j * 32) >> 4;
      u16* vbase = (u16*)Cv + (size_t)(m0 >> 11) * (1024 * 2048);
#pragma unroll
      for (int c = 0; c < 4; ++c) {
        u16x4 o;
#pragma unroll
        for (int rr = 0; rr < 4; ++rr) o[rr] = f2bf(a[4 * c + rr] + bn);
        u16* dst = vbase + ((size_t)nnT * 128 + sb + (c >> 1)) * 512 +
                   (l31 + 32 * (c & 1)) * 8 + 4 * g2;
        *(u16x4*)dst = o;
      }
    };
    storeVfm(acc0, 0); storeVfm(acc1, 1);
  } else {
    auto storeRow = [&](const f32x16& a, int j) {
      const int m = m0 + j * 32 + l31;
#pragma unroll
      for (int c = 0; c < 4; ++c) {
        const int nb = n0 + w * 32 + 8 * c + 4 * g2;
        const float4 b4 = *(const float4*)&bias[nb];
        u16x4 o;
        o[0] = f2bf(a[4 * c + 0] + b4.x); o[1] = f2bf(a[4 * c + 1] + b4.y);
        o[2] = f2bf(a[4 * c + 2] + b4.z); o[3] = f2bf(a[4 * c + 3] + b4.w);
        *(u16x4*)((u16*)Cv + (size_t)m * N + nb) = o;
      }
    };
    storeRow(acc0, 0); storeRow(acc1, 1);
  }
}

// ---------------------------------------------------------------------------
// MFMA flash attention: paired-tile counted-vmcnt pipeline with intra-pair
// phase interleave (verified R18 — best flash variant: 45.2us, MfmaUtil 31.5).
// ---------------------------------------------------------------------------
__global__ __launch_bounds__(256, 2) void flash_mfma_k(
    const u16* __restrict__ Qb, const u16* __restrict__ Kf,
    const u16* __restrict__ Vf, u16* __restrict__ Ofm) {
  __shared__ u16 smem[32768];  // 2 pair-buffers x 16384 u16 (2 tiles each)
  const int t    = threadIdx.x;
  const int lane = t & 63;
  const int w    = t >> 6;
  const int l31  = lane & 31, g2 = lane >> 5;
  const int hid = (blockIdx.z * 16 + blockIdx.y) * 16 + blockIdx.x;
  const int sid = (hid & 7) * 64 + (hid >> 3);
  const int h = (sid >> 4) & 15, b = sid >> 8;
  const int q0 = (sid & 15) * 128 + w * 32;

  s16x8 qf0, qf1, qf2, qf3;
  {
    const u16* qp = Qb + ((size_t)(b * Ss + q0 + l31)) * Dd + h * HDh + 8 * g2;
    qf0 = *(const s16x8*)(qp);
    qf1 = *(const s16x8*)(qp + 16);
    qf2 = *(const s16x8*)(qp + 32);
    qf3 = *(const s16x8*)(qp + 48);
  }

  f32x16 accO0, accO1, zacc;
#pragma unroll
  for (int r = 0; r < 16; ++r) { accO0[r] = 0.f; accO1[r] = 0.f; zacc[r] = 0.f; }
  float l_run = 0.f;

  const int f0 = 2 * w, f1 = 2 * w + 1;
  const u16* kg0 = Kf + (((size_t)b * 64 + (f0 >> 2)) * 64 + h * 4 + (f0 & 3)) * 512 + lane * 8;
  const u16* kg1 = Kf + (((size_t)b * 64 + (f1 >> 2)) * 64 + h * 4 + (f1 & 3)) * 512 + lane * 8;
  const u16* vg0 = Vf + (size_t)b * 2097152 + (((size_t)h * 2 + (f0 >> 2)) * 128 + (f0 & 3)) * 512 + lane * 8;
  const u16* vg1 = Vf + (size_t)b * 2097152 + (((size_t)h * 2 + (f1 >> 2)) * 128 + (f1 & 3)) * 512 + lane * 8;

  auto stage_pair = [&](int pb, int kt) {
#pragma unroll
    for (int j = 0; j < 2; ++j) {
      u16* base = &smem[pb * 16384 + j * 8192];
      gload_lds16(kg0 + (size_t)(kt + j) * 65536, base + f0 * 512);
      gload_lds16(kg1 + (size_t)(kt + j) * 65536, base + f1 * 512);
      gload_lds16(vg0 + (size_t)(kt + j) * 2048, base + 4096 + f0 * 512);
      gload_lds16(vg1 + (size_t)(kt + j) * 2048, base + 4096 + f1 * 512);
    }
  };

  auto qk_compute = [&](const u16* sb, f32x16& sc0, f32x16& sc1) {
    const int lb = lane * 8;
    __builtin_amdgcn_s_setprio(1);
    {
      s16x8 ka;
      ka  = *(const s16x8*)&sb[(0 * 4 + 0) * 512 + lb];
      sc0 = __builtin_amdgcn_mfma_f32_32x32x16_bf16(ka, qf0, zacc, 0, 0, 0);
      ka  = *(const s16x8*)&sb[(0 * 4 + 1) * 512 + lb];
      sc0 = __builtin_amdgcn_mfma_f32_32x32x16_bf16(ka, qf1, sc0, 0, 0, 0);
      ka  = *(const s16x8*)&sb[(0 * 4 + 2) * 512 + lb];
      sc0 = __builtin_amdgcn_mfma_f32_32x32x16_bf16(ka, qf2, sc0, 0, 0, 0);
      ka  = *(const s16x8*)&sb[(0 * 4 + 3) * 512 + lb];
      sc0 = __builtin_amdgcn_mfma_f32_32x32x16_bf16(ka, qf3, sc0, 0, 0, 0);
      ka  = *(const s16x8*)&sb[(1 * 4 + 0) * 512 + lb];
      sc1 = __builtin_amdgcn_mfma_f32_32x32x16_bf16(ka, qf0, zacc, 0, 0, 0);
      ka  = *(const s16x8*)&sb[(1 * 4 + 1) * 512 + lb];
      sc1 = __builtin_amdgcn_mfma_f32_32x32x16_bf16(ka, qf1, sc1, 0, 0, 0);
      ka  = *(const s16x8*)&sb[(1 * 4 + 2) * 512 + lb];
      sc1 = __builtin_amdgcn_mfma_f32_32x32x16_bf16(ka, qf2, sc1, 0, 0, 0);
      ka  = *(const s16x8*)&sb[(1 * 4 + 3) * 512 + lb];
      sc1 = __builtin_amdgcn_mfma_f32_32x32x16_bf16(ka, qf3, sc1, 0, 0, 0);
    }
    __builtin_amdgcn_s_setprio(0);
  };

  auto smpv_compute = [&](const u16* sb, const f32x16& sc0, const f32x16& sc1) {
    const int lb = lane * 8;
    float lp = 0.f;
    u32 pw0[4][2];
#pragma unroll
    for (int c = 0; c < 4; ++c) {
      const float e0 = vexp2(sc0[4 * c + 0]);
      const float e1 = vexp2(sc0[4 * c + 1]);
      const float e2 = vexp2(sc0[4 * c + 2]);
      const float e3 = vexp2(sc0[4 * c + 3]);
      lp += (e0 + e1) + (e2 + e3);
      pw0[c][0] = cvt_pk_bf16(e0, e1);
      pw0[c][1] = cvt_pk_bf16(e2, e3);
    }
#pragma unroll
    for (int s = 0; s < 2; ++s) {
      const int cb = 2 * (s & 1);
      u32 A0w = pw0[cb][0], B0w = pw0[cb + 1][0];
      u32 A1w = pw0[cb][1], B1w = pw0[cb + 1][1];
      asm("v_permlane32_swap_b32 %0, %1" : "+v"(A0w), "+v"(B0w));
      asm("v_permlane32_swap_b32 %0, %1" : "+v"(A1w), "+v"(B1w));
      u32x4 pv;
      pv[0] = A0w; pv[1] = A1w; pv[2] = B0w; pv[3] = B1w;
      const s16x8 pf = __builtin_bit_cast(s16x8, pv);
      const s16x8 v0 = *(const s16x8*)&sb[4096 + (0 * 4 + s) * 512 + lb];
      const s16x8 v1 = *(const s16x8*)&sb[4096 + (1 * 4 + s) * 512 + lb];
      __builtin_amdgcn_s_setprio(1);
      accO0 = __builtin_amdgcn_mfma_f32_32x32x16_bf16(v0, pf, accO0, 0, 0, 0);
      accO1 = __builtin_amdgcn_mfma_f32_32x32x16_bf16(v1, pf, accO1, 0, 0, 0);
      __builtin_amdgcn_s_setprio(0);
    }
    u32 pw1[4][2];
#pragma unroll
    for (int c = 0; c < 4; ++c) {
      const float e0 = vexp2(sc1[4 * c + 0]);
      const float e1 = vexp2(sc1[4 * c + 1]);
      const float e2 = vexp2(sc1[4 * c + 2]);
      const float e3 = vexp2(sc1[4 * c + 3]);
      lp += (e0 + e1) + (e2 + e3);
      pw1[c][0] = cvt_pk_bf16(e0, e1);
      pw1[c][1] = cvt_pk_bf16(e2, e3);
    }
    l_run += lp;
#pragma unroll
    for (int s = 2; s < 4; ++s) {
      const int cb = 2 * (s & 1);
      u32 A0w = pw1[cb][0], B0w = pw1[cb + 1][0];
      u32 A1w = pw1[cb][1], B1w = pw1[cb + 1][1];
      asm("v_permlane32_swap_b32 %0, %1" : "+v"(A0w), "+v"(B0w));
      asm("v_permlane32_swap_b32 %0, %1" : "+v"(A1w), "+v"(B1w));
      u32x4 pv;
      pv[0] = A0w; pv[1] = A1w; pv[2] = B0w; pv[3] = B1w;
      const s16x8 pf = __builtin_bit_cast(s16x8, pv);
      const s16x8 v0 = *(const s16x8*)&sb[4096 + (0 * 4 + s) * 512 + lb];
      const s16x8 v1 = *(const s16x8*)&sb[4096 + (1 * 4 + s) * 512 + lb];
      __builtin_amdgcn_s_setprio(1);
      accO0 = __builtin_amdgcn_mfma_f32_32x32x16_bf16(v0, pf, accO0, 0, 0, 0);
      accO1 = __builtin_amdgcn_mfma_f32_32x32x16_bf16(v1, pf, accO1, 0, 0, 0);
      __builtin_amdgcn_s_setprio(0);
    }
  };

  stage_pair(0, 0);
  stage_pair(1, 2);

  for (int i = 0; i < 16; ++i) {
    const int pb = i & 1;
    if (i < 15) asm volatile("s_waitcnt vmcnt(8)" ::: "memory");
    else        asm volatile("s_waitcnt vmcnt(0)" ::: "memory");
    __builtin_amdgcn_s_barrier();
    const u16* sbA = &smem[pb * 16384];
    const u16* sbB = &smem[pb * 16384 + 8192];
    f32x16 scA0, scA1, scB0, scB1;
    qk_compute(sbA, scA0, scA1);
    qk_compute(sbB, scB0, scB1);
    smpv_compute(sbA, scA0, scA1);
    smpv_compute(sbB, scB0, scB1);
    if (i <= 13) {
      __builtin_amdgcn_s_barrier();
      stage_pair(pb, 2 * (i + 2));
    }
  }

  __syncthreads();

  const float l_tot = l_run + __shfl_xor(l_run, 32);
  const float inv = 1.f / l_tot;
  u16* Ol = &smem[w * 2304];
#pragma unroll
  for (int c = 0; c < 4; ++c) {
    u16x4 pk;
#pragma unroll
    for (int rr = 0; rr < 4; ++rr) pk[rr] = f2bf(accO0[4 * c + rr] * inv);
    *(u16x4*)&Ol[l31 * 72 + 0 * 32 + c * 8 + g2 * 4] = pk;
#pragma unroll
    for (int rr = 0; rr < 4; ++rr) pk[rr] = f2bf(accO1[4 * c + rr] * inv);
    *(u16x4*)&Ol[l31 * 72 + 1 * 32 + c * 8 + g2 * 4] = pk;
  }
  const size_t m32 = (size_t)((b * Ss + q0) >> 5);
#pragma unroll
  for (int s = 0; s < 4; ++s) {
    const u16x8 vv = *(const u16x8*)&Ol[l31 * 72 + s * 16 + g2 * 8];
    *(u16x8*)(Ofm + (m32 * 64 + h * 4 + s) * 512 + lane * 8) = vv;
  }
}

// ---------------------------------------------------------------------------
// Residual + LayerNorm; x1 (o-projection output) is bf16.
// ---------------------------------------------------------------------------
__global__ __launch_bounds__(256) void resid_ln_k(const float* __restrict__ x0,
                                                  const u16* __restrict__ x1,
                                                  const float* __restrict__ gamma,
                                                  const float* __restrict__ beta,
                                                  float* __restrict__ out) {
  const int row = blockIdx.x;
  const int t   = threadIdx.x;
  const size_t base = (size_t)row * Dd + t * 4;
  const float4 a = *(const float4*)(x0 + base);
  const u16x4  c = *(const u16x4*)(x1 + base);
  float x[4] = {a.x + bf2f(c[0]), a.y + bf2f(c[1]), a.z + bf2f(c[2]), a.w + bf2f(c[3])};
  float s  = (x[0] + x[1]) + (x[2] + x[3]);
  float s2 = fmaf(x[0], x[0], fmaf(x[1], x[1], fmaf(x[2], x[2], x[3] * x[3])));
#pragma unroll
  for (int m = 1; m < 64; m <<= 1) {
    s  += __shfl_xor(s, m);
    s2 += __shfl_xor(s2, m);
  }
  __shared__ float red[8];
  const int wave = t >> 6;
  if ((t & 63) == 0) {
    red[wave]     = s;
    red[wave + 4] = s2;
  }
  __syncthreads();
  s  = (red[0] + red[1]) + (red[2] + red[3]);
  s2 = (red[4] + red[5]) + (red[6] + red[7]);
  const float mu  = s * (1.f / Dd);
  const float var = s2 * (1.f / Dd) - mu * mu;
  const float rs  = rsqrtf(var + kEps);
  const float4 g  = *(const float4*)(gamma + t * 4);
  const float4 be = *(const float4*)(beta + t * 4);
  float4 o;
  o.x = (x[0] - mu) * rs * g.x + be.x;
  o.y = (x[1] - mu) * rs * g.y + be.y;
  o.z = (x[2] - mu) * rs * g.z + be.z;
  o.w = (x[3] - mu) * rs * g.w + be.w;
  *(float4*)(out + base) = o;
}

// ---------------------------------------------------------------------------
// Memory plan (race-free, verified R13-R18):
// d_out (16 MB):
//   Xq_fm [0,8M), Xk_fm [8,16M)  (dead after QK gemm)
//   -> Ofm [0,8M) (flash output)  -> final LN output overwrites [0,16M).
// ws (32 MB):
//   [0,8M)   Xv_fm (dead after V gemm) -> Qb bf16 row-major
//   [8,16M)  Kf bf16 FM (dead after flash) -> XoB bf16 (oproj out)
//   [16,24M) Vf bf16 FM (per-b V^T) (dead after flash)
//   [24,32M) Wq/Wk/Wv/Wo fragment-major bf16 (2 MB each)
// ---------------------------------------------------------------------------
extern "C" void kernel_launch(void* const* d_in, const int* in_sizes, int n_in,
                              void* d_out, int out_size, void* d_ws,
                              size_t ws_size, hipStream_t stream) {
  const float* query = (const float*)d_in[0];
  const float* key_  = (const float*)d_in[1];
  const float* value = (const float*)d_in[2];
  const float* Wq = (const float*)d_in[3];
  const float* bq = (const float*)d_in[4];
  const float* Wk = (const float*)d_in[5];
  const float* bk = (const float*)d_in[6];
  const float* Wv = (const float*)d_in[7];
  const float* bv = (const float*)d_in[8];
  const float* Wo = (const float*)d_in[9];
  const float* bo = (const float*)d_in[10];
  const float* gamma = (const float*)d_in[11];
  const float* beta  = (const float*)d_in[12];
  float* out = (float*)d_out;

  char* ws = (char*)d_ws;
  u16* Xv  = (u16*)(ws + (size_t)0);
  u16* Qb  = (u16*)(ws + (size_t)0);                   // over dead Xv
  u16* Kf  = (u16*)(ws + (size_t)8 * 1024 * 1024);
  u16* XoB = (u16*)(ws + (size_t)8 * 1024 * 1024);     // over dead Kf
  u16* Vf  = (u16*)(ws + (size_t)16 * 1024 * 1024);
  u16* WfB = (u16*)(ws + (size_t)24 * 1024 * 1024);
  u16* Wqf = WfB;
  u16* Wkf = WfB + (size_t)1 * 1024 * 1024;
  u16* Wvf = WfB + (size_t)2 * 1024 * 1024;
  u16* Wof = WfB + (size_t)3 * 1024 * 1024;
  u16* Xq  = (u16*)d_out;
  u16* Xk  = (u16*)d_out + (size_t)Mr * Dd;
  u16* Ofm = (u16*)d_out;                              // over dead Xq

  // 0) all activations + weights -> fragment-major bf16, ONE launch
  pack_all_fm<<<4096, 256, 0, stream>>>(query, key_, value, Wq, Wk, Wv, Wo,
                                        Xq, Xk, Xv, WfB);
  // 1) V projection -> V^T in FM layout (Vf); split-M grid (2 blocks/CU)
  gemm_half_k<1><<<dim3(8, 64), 256, 0, stream>>>(Xv, Wvf, bv, Vf);
  // 2) Q,K projections: z0 Q row-major (pre-scaled), z1 K in FM layout
  gemm_qk_k<<<dim3(8, 32, 2), 256, 0, stream>>>(
      Xq, Xk, Wqf, Wkf, bq, bk, Qb, Kf, kQScale, 1.f);
  // 3) MFMA flash attention (phase-interleaved paired pipeline) -> Ofm
  flash_mfma_k<<<dim3(16, 16, 2), 256, 0, stream>>>(Qb, Kf, Vf, Ofm);
  // 4) output projection (fm A, bf16 out over dead Kf); split-M grid
  gemm_half_k<0><<<dim3(8, 64), 256, 0, stream>>>(Ofm, Wof, bo, XoB);
  // 5) residual + LayerNorm (overwrites d_out with the final result)
  resid_ln_k<<<Mr, 256, 0, stream>>>(query, XoB, gamma, beta, out);
}

// Round 20
// 124.921 us; speedup vs baseline: 1.1623x; 1.1623x over previous
//
#include <hip/hip_runtime.h>
#include <hip/hip_bf16.h>

#define DEVI __device__ __forceinline__

// Problem constants (fixed by the reference)
constexpr int Bb  = 2;
constexpr int Ss  = 2048;
constexpr int Dd  = 1024;
constexpr int Hh  = 16;
constexpr int HDh = 64;
constexpr int Mr  = Bb * Ss;      // 4096 rows in all GEMMs
constexpr float kEps = 1e-5f;
// kScale * log2(e), folded into the Q projection so flash uses raw 2^x
constexpr float kQScale = 0.18033688011112043f;

typedef unsigned short u16;
typedef unsigned int   u32;
typedef u16 u16x8 __attribute__((ext_vector_type(8)));
typedef u16 u16x4 __attribute__((ext_vector_type(4)));
typedef __attribute__((ext_vector_type(8)))  short s16x8;
typedef __attribute__((ext_vector_type(16))) float f32x16;
typedef __attribute__((ext_vector_type(4)))  u32   u32x4;

DEVI float bf2f(u16 u) {
  return __builtin_bit_cast(float, ((unsigned int)u) << 16);
}
DEVI u16 f2bf(float f) {  // round-to-nearest-even, finite values only
  unsigned int x = __builtin_bit_cast(unsigned int, f);
  return (u16)((x + 0x7FFFu + ((x >> 16) & 1u)) >> 16);
}
DEVI u32 cvt_pk_bf16(float a, float b) {  // HW packed f32x2 -> bf16x2, RNE
  u32 r;
  asm("v_cvt_pk_bf16_f32 %0, %1, %2" : "=v"(r) : "v"(a), "v"(b));
  return r;
}
DEVI float vexp2(float x) {  // 2^x on the TRANS pipe, no pre-multiply
  float r;
  asm("v_exp_f32 %0, %1" : "=v"(r) : "v"(x));
  return r;
}

// global -> LDS direct copy, 16B per lane (flash only).
DEVI void gload_lds16(const void* g, void* l) {
  __builtin_amdgcn_global_load_lds(
      (const __attribute__((address_space(1))) unsigned int*)(unsigned long long)(size_t)g,
      (__attribute__((address_space(3))) unsigned int*)(unsigned int)(size_t)l,
      16, 0, 0);
}

// ===========================================================================
// FRAGMENT-MAJOR (fm) layout, bf16 matrix [R][C]: elem [r][c] lives at u16
// offset ((r>>5)*(C/16) + (c>>4))*512 + ((r&31) + 32*((c>>3)&1))*8 + (c&7).
// A wave-load of one 32x16 frag = base + lane*16B, fully coalesced (1KB).
// ===========================================================================

// ---------------------------------------------------------------------------
// pack_all_fm: ONE launch packs 3 activations (f32 [4096][1024] -> fm bf16)
// and 4 weights (f32 [k][n] -> fm bf16 B-layout). Flat grid of 4096 blocks.
// ---------------------------------------------------------------------------
__global__ __launch_bounds__(256) void pack_all_fm(
    const float* __restrict__ X0, const float* __restrict__ X1,
    const float* __restrict__ X2,
    const float* __restrict__ W0, const float* __restrict__ W1,
    const float* __restrict__ W2, const float* __restrict__ W3,
    u16* __restrict__ Y0, u16* __restrict__ Y1, u16* __restrict__ Y2,
    u16* __restrict__ WfmBase) {
  __shared__ u16 Tl[64 * 64];
  const int t   = threadIdx.x;
  const int gid = blockIdx.x;
  if (gid < 3072) {
    // -------- activation pack --------
    const int z   = gid >> 10;
    const int rem = gid & 1023;
    const int r0  = (rem >> 4) * 64, k0 = (rem & 15) * 64;
    const float* X = z == 0 ? X0 : z == 1 ? X1 : X2;
    u16*         Y = z == 0 ? Y0 : z == 1 ? Y1 : Y2;
#pragma unroll
    for (int i = 0; i < 4; ++i) {
      const int idx = t + i * 256;
      const int r = idx >> 4, c4 = (idx & 15) << 2;
      const float4 v = *(const float4*)(X + (size_t)(r0 + r) * 1024 + k0 + c4);
      u16x4 p;
      p[0] = f2bf(v.x); p[1] = f2bf(v.y); p[2] = f2bf(v.z); p[3] = f2bf(v.w);
      *(u16x4*)&Tl[r * 64 + (c4 ^ (8 * (r & 7)))] = p;
    }
    __syncthreads();
#pragma unroll
    for (int i = 0; i < 2; ++i) {
      const int slot = t + i * 256;
      const int f = slot >> 6, l = slot & 63;
      const int l31 = l & 31, g2 = l >> 5;
      const int r = (f >> 2) * 32 + l31;
      const int c = (f & 3) * 16 + g2 * 8;
      const u16x8 v = *(const u16x8*)&Tl[r * 64 + (c ^ (8 * (r & 7)))];
      const size_t t32 = (size_t)(r0 >> 5) + (f >> 2);
      const int s = (k0 >> 4) + (f & 3);
      *(u16x8*)(Y + (t32 * 64 + s) * 512 + l * 8) = v;
    }
  } else {
    // -------- weight pack --------
    const int wz  = (gid - 3072) >> 8;
    const int rem = (gid - 3072) & 255;
    const int n0  = (rem >> 4) * 64, k0 = (rem & 15) * 64;
    const float* W = wz == 0 ? W0 : wz == 1 ? W1 : wz == 2 ? W2 : W3;
    u16* out = WfmBase + (size_t)wz * 1024 * 1024;
#pragma unroll
    for (int i = 0; i < 4; ++i) {
      const int idx = t + i * 256;
      const int r = idx >> 4, c4 = (idx & 15) << 2;   // r = k-idx, c = n-idx
      const float4 v = *(const float4*)(W + (size_t)(k0 + r) * 1024 + n0 + c4);
      u16x4 p;
      p[0] = f2bf(v.x); p[1] = f2bf(v.y); p[2] = f2bf(v.z); p[3] = f2bf(v.w);
      *(u16x4*)&Tl[r * 64 + (c4 ^ (8 * (r & 7)))] = p;
    }
    __syncthreads();
#pragma unroll
    for (int i = 0; i < 2; ++i) {
      const int slot = t + i * 256;
      const int f = slot >> 6, l = slot & 63;
      const int l31 = l & 31, g2 = l >> 5;
      const int rbase = (f & 3) * 16 + g2 * 8;         // k within tile
      const int c = (f >> 2) * 32 + l31;               // n within tile
      u16x8 o;
#pragma unroll
      for (int j = 0; j < 8; ++j) {
        const int r = rbase + j;
        o[j] = Tl[r * 64 + (((c & ~3) ^ (8 * (r & 7))) | (c & 3))];
      }
      const size_t n32 = (size_t)(n0 >> 5) + (f >> 2);
      const int s = (k0 >> 4) + (f & 3);
      *(u16x8*)(out + (n32 * 64 + s) * 512 + l * 8) = o;
    }
  }
}

// ---------------------------------------------------------------------------
// Register-staged MFMA GEMM on FRAGMENT-MAJOR inputs, DEPTH-3 pipeline
// (verified R9-R18, 128x128 block). Distinct input/output buffers only.
// MODE 0: bf16 row-major out (esc-scaled)        [o-projection]
// MODE 1: V projection — V^T written in FM layout into Vf (per-b 1024x2048)
// MODE 2: QK fused — z0: bf16 row-major (esc);  z1: K written FM into Kf
// ---------------------------------------------------------------------------
template <int MODE>
__global__ __launch_bounds__(256, 2) void gemm_reg_k(
    const u16* __restrict__ A0, const u16* __restrict__ A1,
    const u16* __restrict__ Wt0, const u16* __restrict__ Wt1,
    const float* b0, const float* b1, void* C0, void* C1,
    float e0, float e1) {
  constexpr int K = 1024, N = 1024;
  const int z = blockIdx.z;
  const u16*   A    = z ? A1 : A0;
  const u16*   Wt   = z ? Wt1 : Wt0;
  const float* bias = z ? b1 : b0;
  void*        Cv   = z ? C1 : C0;
  const float  esc  = z ? e1 : e0;

  const int t = threadIdx.x;
  const int lane = t & 63, w = t >> 6;
  const int l31 = lane & 31, g2 = lane >> 5;
  const int id  = blockIdx.y * 8 + blockIdx.x;
  const int sid = (id & 7) * 32 + (id >> 3);
  const int m0 = (sid >> 3) * 128, n0 = (sid & 7) * 128;
  const int wr = w >> 1, wc = w & 1;

  const u16* a0p = A  + ((size_t)(m0 >> 5) + 2 * wr) * 32768 + lane * 8;
  const u16* a1p = a0p + 32768;
  const u16* w0p = Wt + ((size_t)(n0 >> 5) + 2 * wc) * 32768 + lane * 8;
  const u16* w1p = w0p + 32768;

  f32x16 acc00, acc01, acc10, acc11;
#pragma unroll
  for (int r = 0; r < 16; ++r) { acc00[r] = 0.f; acc01[r] = 0.f; acc10[r] = 0.f; acc11[r] = 0.f; }

  s16x8 X[8], Y[8], Z[8];
  auto loadset = [&](s16x8* R, int k0) {
    const int o = (k0 >> 4) * 512;
    R[0] = *(const s16x8*)(a0p + o);  R[1] = *(const s16x8*)(a0p + o + 512);
    R[2] = *(const s16x8*)(a1p + o);  R[3] = *(const s16x8*)(a1p + o + 512);
    R[4] = *(const s16x8*)(w0p + o);  R[5] = *(const s16x8*)(w0p + o + 512);
    R[6] = *(const s16x8*)(w1p + o);  R[7] = *(const s16x8*)(w1p + o + 512);
  };
  auto compute = [&](const s16x8* R) {
#pragma unroll
    for (int s = 0; s < 2; ++s) {
      if constexpr (MODE == 1) {
        // C col = n (A-op = X)
        acc00 = __builtin_amdgcn_mfma_f32_32x32x16_bf16(R[0 + s], R[4 + s], acc00, 0, 0, 0);
        acc01 = __builtin_amdgcn_mfma_f32_32x32x16_bf16(R[0 + s], R[6 + s], acc01, 0, 0, 0);
        acc10 = __builtin_amdgcn_mfma_f32_32x32x16_bf16(R[2 + s], R[4 + s], acc10, 0, 0, 0);
        acc11 = __builtin_amdgcn_mfma_f32_32x32x16_bf16(R[2 + s], R[6 + s], acc11, 0, 0, 0);
      } else {
        // C col = m (A-op = W)
        acc00 = __builtin_amdgcn_mfma_f32_32x32x16_bf16(R[4 + s], R[0 + s], acc00, 0, 0, 0);
        acc01 = __builtin_amdgcn_mfma_f32_32x32x16_bf16(R[4 + s], R[2 + s], acc01, 0, 0, 0);
        acc10 = __builtin_amdgcn_mfma_f32_32x32x16_bf16(R[6 + s], R[0 + s], acc10, 0, 0, 0);
        acc11 = __builtin_amdgcn_mfma_f32_32x32x16_bf16(R[6 + s], R[2 + s], acc11, 0, 0, 0);
      }
    }
  };

  loadset(X, 0); loadset(Y, 32); loadset(Z, 64);
  int k = 0;
  for (int it = 0; it < 9; ++it, k += 96) {
    compute(X); loadset(X, k + 96);
    compute(Y); loadset(Y, k + 128);
    compute(Z); loadset(Z, k + 160);
  }
  compute(X); loadset(X, 960);
  compute(Y); loadset(Y, 992);
  compute(Z);
  compute(X);
  compute(Y);

  if constexpr (MODE == 1) {
    // V^T in FM layout over per-b matrix [nn=1024][s=2048]
    auto storeVfm = [&](const f32x16& a, int i, int j) {
      const int nn = n0 + (2 * wc + j) * 32 + l31;     // d-feature col
      const float bn = bias[nn];
      const int nnT = (n0 >> 5) + 2 * wc + j;          // nn>>5
      const int sb  = ((m0 & 2047) + (2 * wr + i) * 32) >> 4;  // s base >>4
      u16* vbase = (u16*)Cv + (size_t)(m0 >> 11) * (1024 * 2048);
#pragma unroll
      for (int c = 0; c < 4; ++c) {
        u16x4 o;
#pragma unroll
        for (int rr = 0; rr < 4; ++rr) o[rr] = f2bf(a[4 * c + rr] + bn);
        u16* dst = vbase + ((size_t)nnT * 128 + sb + (c >> 1)) * 512 +
                   (l31 + 32 * (c & 1)) * 8 + 4 * g2;
        *(u16x4*)dst = o;
      }
    };
    storeVfm(acc00, 0, 0); storeVfm(acc01, 0, 1); storeVfm(acc10, 1, 0); storeVfm(acc11, 1, 1);
  } else {
    auto storeRow = [&](const f32x16& a, int i, int j) {  // row-major bf16
      const int m = m0 + (2 * wr + j) * 32 + l31;
#pragma unroll
      for (int c = 0; c < 4; ++c) {
        const int nb = n0 + (2 * wc + i) * 32 + 8 * c + 4 * g2;
        const float4 b4 = *(const float4*)&bias[nb];
        u16x4 o;
        o[0] = f2bf((a[4 * c + 0] + b4.x) * esc); o[1] = f2bf((a[4 * c + 1] + b4.y) * esc);
        o[2] = f2bf((a[4 * c + 2] + b4.z) * esc); o[3] = f2bf((a[4 * c + 3] + b4.w) * esc);
        *(u16x4*)((u16*)Cv + (size_t)m * N + nb) = o;
      }
    };
    auto storeKfm = [&](const f32x16& a, int i, int j) {  // K in FM layout
      const int mt = (m0 >> 5) + 2 * wr + j;              // m>>5
#pragma unroll
      for (int c = 0; c < 4; ++c) {
        const int nb = n0 + (2 * wc + i) * 32 + 8 * c + 4 * g2;
        const float4 b4 = *(const float4*)&bias[nb];
        u16x4 o;
        o[0] = f2bf(a[4 * c + 0] + b4.x); o[1] = f2bf(a[4 * c + 1] + b4.y);
        o[2] = f2bf(a[4 * c + 2] + b4.z); o[3] = f2bf(a[4 * c + 3] + b4.w);
        const int nq = (n0 >> 4) + (2 * wc + i) * 2 + (c >> 1);  // n>>4
        u16* dst = (u16*)Cv + ((size_t)mt * 64 + nq) * 512 +
                   (l31 + 32 * (c & 1)) * 8 + 4 * g2;
        *(u16x4*)dst = o;
      }
    };
    if (MODE == 2 && z == 1) {
      storeKfm(acc00, 0, 0); storeKfm(acc01, 0, 1); storeKfm(acc10, 1, 0); storeKfm(acc11, 1, 1);
    } else {
      storeRow(acc00, 0, 0); storeRow(acc01, 0, 1); storeRow(acc10, 1, 0); storeRow(acc11, 1, 1);
    }
  }
}

// ---------------------------------------------------------------------------
// MFMA flash attention: paired-tile counted-vmcnt pipeline with intra-pair
// phase interleave (verified R18 — best flash variant: 45.2us, MfmaUtil 31.5).
// ---------------------------------------------------------------------------
__global__ __launch_bounds__(256, 2) void flash_mfma_k(
    const u16* __restrict__ Qb, const u16* __restrict__ Kf,
    const u16* __restrict__ Vf, u16* __restrict__ Ofm) {
  __shared__ u16 smem[32768];  // 2 pair-buffers x 16384 u16 (2 tiles each)
  const int t    = threadIdx.x;
  const int lane = t & 63;
  const int w    = t >> 6;
  const int l31  = lane & 31, g2 = lane >> 5;
  const int hid = (blockIdx.z * 16 + blockIdx.y) * 16 + blockIdx.x;
  const int sid = (hid & 7) * 64 + (hid >> 3);
  const int h = (sid >> 4) & 15, b = sid >> 8;
  const int q0 = (sid & 15) * 128 + w * 32;

  s16x8 qf0, qf1, qf2, qf3;
  {
    const u16* qp = Qb + ((size_t)(b * Ss + q0 + l31)) * Dd + h * HDh + 8 * g2;
    qf0 = *(const s16x8*)(qp);
    qf1 = *(const s16x8*)(qp + 16);
    qf2 = *(const s16x8*)(qp + 32);
    qf3 = *(const s16x8*)(qp + 48);
  }

  f32x16 accO0, accO1, zacc;
#pragma unroll
  for (int r = 0; r < 16; ++r) { accO0[r] = 0.f; accO1[r] = 0.f; zacc[r] = 0.f; }
  float l_run = 0.f;

  const int f0 = 2 * w, f1 = 2 * w + 1;
  const u16* kg0 = Kf + (((size_t)b * 64 + (f0 >> 2)) * 64 + h * 4 + (f0 & 3)) * 512 + lane * 8;
  const u16* kg1 = Kf + (((size_t)b * 64 + (f1 >> 2)) * 64 + h * 4 + (f1 & 3)) * 512 + lane * 8;
  const u16* vg0 = Vf + (size_t)b * 2097152 + (((size_t)h * 2 + (f0 >> 2)) * 128 + (f0 & 3)) * 512 + lane * 8;
  const u16* vg1 = Vf + (size_t)b * 2097152 + (((size_t)h * 2 + (f1 >> 2)) * 128 + (f1 & 3)) * 512 + lane * 8;

  auto stage_pair = [&](int pb, int kt) {
#pragma unroll
    for (int j = 0; j < 2; ++j) {
      u16* base = &smem[pb * 16384 + j * 8192];
      gload_lds16(kg0 + (size_t)(kt + j) * 65536, base + f0 * 512);
      gload_lds16(kg1 + (size_t)(kt + j) * 65536, base + f1 * 512);
      gload_lds16(vg0 + (size_t)(kt + j) * 2048, base + 4096 + f0 * 512);
      gload_lds16(vg1 + (size_t)(kt + j) * 2048, base + 4096 + f1 * 512);
    }
  };

  auto qk_compute = [&](const u16* sb, f32x16& sc0, f32x16& sc1) {
    const int lb = lane * 8;
    __builtin_amdgcn_s_setprio(1);
    {
      s16x8 ka;
      ka  = *(const s16x8*)&sb[(0 * 4 + 0) * 512 + lb];
      sc0 = __builtin_amdgcn_mfma_f32_32x32x16_bf16(ka, qf0, zacc, 0, 0, 0);
      ka  = *(const s16x8*)&sb[(0 * 4 + 1) * 512 + lb];
      sc0 = __builtin_amdgcn_mfma_f32_32x32x16_bf16(ka, qf1, sc0, 0, 0, 0);
      ka  = *(const s16x8*)&sb[(0 * 4 + 2) * 512 + lb];
      sc0 = __builtin_amdgcn_mfma_f32_32x32x16_bf16(ka, qf2, sc0, 0, 0, 0);
      ka  = *(const s16x8*)&sb[(0 * 4 + 3) * 512 + lb];
      sc0 = __builtin_amdgcn_mfma_f32_32x32x16_bf16(ka, qf3, sc0, 0, 0, 0);
      ka  = *(const s16x8*)&sb[(1 * 4 + 0) * 512 + lb];
      sc1 = __builtin_amdgcn_mfma_f32_32x32x16_bf16(ka, qf0, zacc, 0, 0, 0);
      ka  = *(const s16x8*)&sb[(1 * 4 + 1) * 512 + lb];
      sc1 = __builtin_amdgcn_mfma_f32_32x32x16_bf16(ka, qf1, sc1, 0, 0, 0);
      ka  = *(const s16x8*)&sb[(1 * 4 + 2) * 512 + lb];
      sc1 = __builtin_amdgcn_mfma_f32_32x32x16_bf16(ka, qf2, sc1, 0, 0, 0);
      ka  = *(const s16x8*)&sb[(1 * 4 + 3) * 512 + lb];
      sc1 = __builtin_amdgcn_mfma_f32_32x32x16_bf16(ka, qf3, sc1, 0, 0, 0);
    }
    __builtin_amdgcn_s_setprio(0);
  };

  auto smpv_compute = [&](const u16* sb, const f32x16& sc0, const f32x16& sc1) {
    const int lb = lane * 8;
    float lp = 0.f;
    u32 pw0[4][2];
#pragma unroll
    for (int c = 0; c < 4; ++c) {
      const float e0 = vexp2(sc0[4 * c + 0]);
      const float e1 = vexp2(sc0[4 * c + 1]);
      const float e2 = vexp2(sc0[4 * c + 2]);
      const float e3 = vexp2(sc0[4 * c + 3]);
      lp += (e0 + e1) + (e2 + e3);
      pw0[c][0] = cvt_pk_bf16(e0, e1);
      pw0[c][1] = cvt_pk_bf16(e2, e3);
    }
#pragma unroll
    for (int s = 0; s < 2; ++s) {
      const int cb = 2 * (s & 1);
      u32 A0w = pw0[cb][0], B0w = pw0[cb + 1][0];
      u32 A1w = pw0[cb][1], B1w = pw0[cb + 1][1];
      asm("v_permlane32_swap_b32 %0, %1" : "+v"(A0w), "+v"(B0w));
      asm("v_permlane32_swap_b32 %0, %1" : "+v"(A1w), "+v"(B1w));
      u32x4 pv;
      pv[0] = A0w; pv[1] = A1w; pv[2] = B0w; pv[3] = B1w;
      const s16x8 pf = __builtin_bit_cast(s16x8, pv);
      const s16x8 v0 = *(const s16x8*)&sb[4096 + (0 * 4 + s) * 512 + lb];
      const s16x8 v1 = *(const s16x8*)&sb[4096 + (1 * 4 + s) * 512 + lb];
      __builtin_amdgcn_s_setprio(1);
      accO0 = __builtin_amdgcn_mfma_f32_32x32x16_bf16(v0, pf, accO0, 0, 0, 0);
      accO1 = __builtin_amdgcn_mfma_f32_32x32x16_bf16(v1, pf, accO1, 0, 0, 0);
      __builtin_amdgcn_s_setprio(0);
    }
    u32 pw1[4][2];
#pragma unroll
    for (int c = 0; c < 4; ++c) {
      const float e0 = vexp2(sc1[4 * c + 0]);
      const float e1 = vexp2(sc1[4 * c + 1]);
      const float e2 = vexp2(sc1[4 * c + 2]);
      const float e3 = vexp2(sc1[4 * c + 3]);
      lp += (e0 + e1) + (e2 + e3);
      pw1[c][0] = cvt_pk_bf16(e0, e1);
      pw1[c][1] = cvt_pk_bf16(e2, e3);
    }
    l_run += lp;
#pragma unroll
    for (int s = 2; s < 4; ++s) {
      const int cb = 2 * (s & 1);
      u32 A0w = pw1[cb][0], B0w = pw1[cb + 1][0];
      u32 A1w = pw1[cb][1], B1w = pw1[cb + 1][1];
      asm("v_permlane32_swap_b32 %0, %1" : "+v"(A0w), "+v"(B0w));
      asm("v_permlane32_swap_b32 %0, %1" : "+v"(A1w), "+v"(B1w));
      u32x4 pv;
      pv[0] = A0w; pv[1] = A1w; pv[2] = B0w; pv[3] = B1w;
      const s16x8 pf = __builtin_bit_cast(s16x8, pv);
      const s16x8 v0 = *(const s16x8*)&sb[4096 + (0 * 4 + s) * 512 + lb];
      const s16x8 v1 = *(const s16x8*)&sb[4096 + (1 * 4 + s) * 512 + lb];
      __builtin_amdgcn_s_setprio(1);
      accO0 = __builtin_amdgcn_mfma_f32_32x32x16_bf16(v0, pf, accO0, 0, 0, 0);
      accO1 = __builtin_amdgcn_mfma_f32_32x32x16_bf16(v1, pf, accO1, 0, 0, 0);
      __builtin_amdgcn_s_setprio(0);
    }
  };

  stage_pair(0, 0);
  stage_pair(1, 2);

  for (int i = 0; i < 16; ++i) {
    const int pb = i & 1;
    if (i < 15) asm volatile("s_waitcnt vmcnt(8)" ::: "memory");
    else        asm volatile("s_waitcnt vmcnt(0)" ::: "memory");
    __builtin_amdgcn_s_barrier();
    const u16* sbA = &smem[pb * 16384];
    const u16* sbB = &smem[pb * 16384 + 8192];
    f32x16 scA0, scA1, scB0, scB1;
    qk_compute(sbA, scA0, scA1);
    qk_compute(sbB, scB0, scB1);
    smpv_compute(sbA, scA0, scA1);
    smpv_compute(sbB, scB0, scB1);
    if (i <= 13) {
      __builtin_amdgcn_s_barrier();
      stage_pair(pb, 2 * (i + 2));
    }
  }

  __syncthreads();

  const float l_tot = l_run + __shfl_xor(l_run, 32);
  const float inv = 1.f / l_tot;
  u16* Ol = &smem[w * 2304];
#pragma unroll
  for (int c = 0; c < 4; ++c) {
    u16x4 pk;
#pragma unroll
    for (int rr = 0; rr < 4; ++rr) pk[rr] = f2bf(accO0[4 * c + rr] * inv);
    *(u16x4*)&Ol[l31 * 72 + 0 * 32 + c * 8 + g2 * 4] = pk;
#pragma unroll
    for (int rr = 0; rr < 4; ++rr) pk[rr] = f2bf(accO1[4 * c + rr] * inv);
    *(u16x4*)&Ol[l31 * 72 + 1 * 32 + c * 8 + g2 * 4] = pk;
  }
  const size_t m32 = (size_t)((b * Ss + q0) >> 5);
#pragma unroll
  for (int s = 0; s < 4; ++s) {
    const u16x8 vv = *(const u16x8*)&Ol[l31 * 72 + s * 16 + g2 * 8];
    *(u16x8*)(Ofm + (m32 * 64 + h * 4 + s) * 512 + lane * 8) = vv;
  }
}

// ---------------------------------------------------------------------------
// Residual + LayerNorm; x1 (o-projection output) is bf16.
// ---------------------------------------------------------------------------
__global__ __launch_bounds__(256) void resid_ln_k(const float* __restrict__ x0,
                                                  const u16* __restrict__ x1,
                                                  const float* __restrict__ gamma,
                                                  const float* __restrict__ beta,
                                                  float* __restrict__ out) {
  const int row = blockIdx.x;
  const int t   = threadIdx.x;
  const size_t base = (size_t)row * Dd + t * 4;
  const float4 a = *(const float4*)(x0 + base);
  const u16x4  c = *(const u16x4*)(x1 + base);
  float x[4] = {a.x + bf2f(c[0]), a.y + bf2f(c[1]), a.z + bf2f(c[2]), a.w + bf2f(c[3])};
  float s  = (x[0] + x[1]) + (x[2] + x[3]);
  float s2 = fmaf(x[0], x[0], fmaf(x[1], x[1], fmaf(x[2], x[2], x[3] * x[3])));
#pragma unroll
  for (int m = 1; m < 64; m <<= 1) {
    s  += __shfl_xor(s, m);
    s2 += __shfl_xor(s2, m);
  }
  __shared__ float red[8];
  const int wave = t >> 6;
  if ((t & 63) == 0) {
    red[wave]     = s;
    red[wave + 4] = s2;
  }
  __syncthreads();
  s  = (red[0] + red[1]) + (red[2] + red[3]);
  s2 = (red[4] + red[5]) + (red[6] + red[7]);
  const float mu  = s * (1.f / Dd);
  const float var = s2 * (1.f / Dd) - mu * mu;
  const float rs  = rsqrtf(var + kEps);
  const float4 g  = *(const float4*)(gamma + t * 4);
  const float4 be = *(const float4*)(beta + t * 4);
  float4 o;
  o.x = (x[0] - mu) * rs * g.x + be.x;
  o.y = (x[1] - mu) * rs * g.y + be.y;
  o.z = (x[2] - mu) * rs * g.z + be.z;
  o.w = (x[3] - mu) * rs * g.w + be.w;
  *(float4*)(out + base) = o;
}

// ---------------------------------------------------------------------------
// Memory plan (race-free, verified R13-R18):
// d_out (16 MB):
//   Xq_fm [0,8M), Xk_fm [8,16M)  (dead after QK gemm)
//   -> Ofm [0,8M) (flash output)  -> final LN output overwrites [0,16M).
// ws (32 MB):
//   [0,8M)   Xv_fm (dead after V gemm) -> Qb bf16 row-major
//   [8,16M)  Kf bf16 FM (dead after flash) -> XoB bf16 (oproj out)
//   [16,24M) Vf bf16 FM (per-b V^T) (dead after flash)
//   [24,32M) Wq/Wk/Wv/Wo fragment-major bf16 (2 MB each)
// ---------------------------------------------------------------------------
extern "C" void kernel_launch(void* const* d_in, const int* in_sizes, int n_in,
                              void* d_out, int out_size, void* d_ws,
                              size_t ws_size, hipStream_t stream) {
  const float* query = (const float*)d_in[0];
  const float* key_  = (const float*)d_in[1];
  const float* value = (const float*)d_in[2];
  const float* Wq = (const float*)d_in[3];
  const float* bq = (const float*)d_in[4];
  const float* Wk = (const float*)d_in[5];
  const float* bk = (const float*)d_in[6];
  const float* Wv = (const float*)d_in[7];
  const float* bv = (const float*)d_in[8];
  const float* Wo = (const float*)d_in[9];
  const float* bo = (const float*)d_in[10];
  const float* gamma = (const float*)d_in[11];
  const float* beta  = (const float*)d_in[12];
  float* out = (float*)d_out;

  char* ws = (char*)d_ws;
  u16* Xv  = (u16*)(ws + (size_t)0);
  u16* Qb  = (u16*)(ws + (size_t)0);                   // over dead Xv
  u16* Kf  = (u16*)(ws + (size_t)8 * 1024 * 1024);
  u16* XoB = (u16*)(ws + (size_t)8 * 1024 * 1024);     // over dead Kf
  u16* Vf  = (u16*)(ws + (size_t)16 * 1024 * 1024);
  u16* WfB = (u16*)(ws + (size_t)24 * 1024 * 1024);
  u16* Wqf = WfB;
  u16* Wkf = WfB + (size_t)1 * 1024 * 1024;
  u16* Wvf = WfB + (size_t)2 * 1024 * 1024;
  u16* Wof = WfB + (size_t)3 * 1024 * 1024;
  u16* Xq  = (u16*)d_out;
  u16* Xk  = (u16*)d_out + (size_t)Mr * Dd;
  u16* Ofm = (u16*)d_out;                              // over dead Xq

  // 0) all activations + weights -> fragment-major bf16, ONE launch
  pack_all_fm<<<4096, 256, 0, stream>>>(query, key_, value, Wq, Wk, Wv, Wo,
                                        Xq, Xk, Xv, WfB);
  // 1) V projection -> V^T in FM layout (Vf)
  gemm_reg_k<1><<<dim3(8, 32, 1), 256, 0, stream>>>(
      Xv, Xv, Wvf, Wvf, bv, bv, Vf, Vf, 1.f, 1.f);
  // 2) Q,K projections: z0 Q row-major (pre-scaled), z1 K in FM layout
  gemm_reg_k<2><<<dim3(8, 32, 2), 256, 0, stream>>>(
      Xq, Xk, Wqf, Wkf, bq, bk, Qb, Kf, kQScale, 1.f);
  // 3) MFMA flash attention (phase-interleaved paired pipeline) -> Ofm
  flash_mfma_k<<<dim3(16, 16, 2), 256, 0, stream>>>(Qb, Kf, Vf, Ofm);
  // 4) output projection (fm A, bf16 out over dead Kf)
  gemm_reg_k<0><<<dim3(8, 32, 1), 256, 0, stream>>>(
      Ofm, Ofm, Wof, Wof, bo, bo, XoB, XoB, 1.f, 1.f);
  // 5) residual + LayerNorm (overwrites d_out with the final result)
  resid_ln_k<<<Mr, 256, 0, stream>>>(query, XoB, gamma, beta, out);
}